// Round 15
// baseline (403.548 us; speedup 1.0000x reference)
//
#include <hip/hip_runtime.h>

#define NROWS 262144
#define NE 5
#define CAP 57344                 // per-expert capacity (mean 52429, ~24 sigma)
#define NCH 4096                  // 64-row hist chunks
#define BPE 102                   // mlp blocks per expert (510 total ~ 2/CU)
#define CHUNK 256                 // rows per mlp block-iteration (8 waves x 32)
#define CPAD 16                   // counter stride in ints

typedef __attribute__((ext_vector_type(8))) short short8;
typedef __attribute__((ext_vector_type(8))) unsigned short ushort8;
typedef __attribute__((ext_vector_type(4))) float f32x4;
// 16B vector load with only 4B alignment guarantee (f starts at +4B in a row)
typedef __attribute__((ext_vector_type(4), aligned(4))) float f32x4u;

__device__ __forceinline__ unsigned short f2bf(float x) {
  unsigned u = __float_as_uint(x);
  u += 0x7FFF + ((u >> 16) & 1);   // round-to-nearest-even
  return (unsigned short)(u >> 16);
}
__device__ __forceinline__ int eclass(float t) {
  return (t >= 0.2f) + (t >= 0.4f) + (t >= 0.6f) + (t >= 0.8f);
}

// ---- kernel 1: W1,W2 -> bf16 in the SWIZZLED fragment layout ---------------
// Per expert: 16384 ushorts W1 then 16384 W2. Element (col j, k) at byte
// ((j*256 + k*2) ^ ((j&7)<<4)) within its layer. 320 KB total: L2-resident.
__global__ __launch_bounds__(256) void convw(const float* __restrict__ W1,
                                             const float* __restrict__ W2,
                                             unsigned short* __restrict__ Wswz) {
  int idx = blockIdx.x * 256 + threadIdx.x;       // 0 .. 163839
  int which = idx / 81920;
  int rem = idx % 81920;
  int e = rem / 16384;
  int jk = rem % 16384;
  int j = jk >> 7;                // output col
  int k = jk & 127;               // k index
  const float* W = which ? W2 : W1;
  int byteoff = (j * 256 + k * 2) ^ ((j & 7) << 4);
  Wswz[(size_t)e * 32768 + which * 16384 + (byteoff >> 1)] =
      f2bf(W[(size_t)e * 16384 + k * 128 + j]);
}

// ---- kernel A: extract t + per-64-row-chunk expert histogram ---------------
__global__ __launch_bounds__(256) void thist(const float* __restrict__ x,
                                             float* __restrict__ tcomp,
                                             int* __restrict__ hist) {
  __shared__ int hS[4][NE];
  int tid = threadIdx.x;
  int r = blockIdx.x * 256 + tid;
  if (tid < 20) hS[tid / NE][tid % NE] = 0;
  float t = x[(size_t)r * 129];
  int e = eclass(t);
  tcomp[r] = t;
  __syncthreads();
  atomicAdd(&hS[tid >> 6][e], 1);
  __syncthreads();
  if (tid < 20) {
    int sub = tid / NE, ee = tid % NE;
    hist[ee * NCH + blockIdx.x * 4 + sub] = hS[sub][ee];
  }
}

// ---- kernel B: parallel exclusive prefix per expert (5 blocks x 256) -------
__global__ __launch_bounds__(256) void scan(const int* __restrict__ hist,
                                            int* __restrict__ boff,
                                            int* __restrict__ cnt) {
  __shared__ int wsum[4];
  int e = blockIdx.x;
  int tid = threadIdx.x;
  int lane = tid & 63, wv = tid >> 6;

  int v[16];
  int s = 0;
  const int* h = hist + e * NCH + tid * 16;
#pragma unroll
  for (int j = 0; j < 16; ++j) { v[j] = h[j]; s += v[j]; }

  int sc = s;
#pragma unroll
  for (int off = 1; off < 64; off <<= 1) {
    int nv = __shfl_up(sc, off);
    if (lane >= off) sc += nv;
  }
  if (lane == 63) wsum[wv] = sc;
  __syncthreads();
  int wexc = 0;
  for (int k = 0; k < wv; ++k) wexc += wsum[k];
  int run = wexc + sc - s;
  int* bo = boff + e * NCH + tid * 16;
#pragma unroll
  for (int j = 0; j < 16; ++j) { bo[j] = run; run += v[j]; }
  if (tid == 255) cnt[e * CPAD] = run;
}

// ---- kernel C: build permutation only (tcb + ridb) -------------------------
__global__ __launch_bounds__(256) void perm(const float* __restrict__ tcomp,
                                            const int* __restrict__ boff,
                                            float* __restrict__ tcb,
                                            int* __restrict__ ridb) {
  __shared__ int lc[4][NE];
  int tid = threadIdx.x;
  int blk = blockIdx.x;
  int r = blk * 256 + tid;
  int sub = tid >> 6;
  if (tid < 20) lc[tid / NE][tid % NE] = 0;
  float t = tcomp[r];
  int e = eclass(t);
  __syncthreads();
  int lp = atomicAdd(&lc[sub][e], 1);
  int d = e * CAP + min(boff[e * NCH + blk * 4 + sub] + lp, CAP - 1);
  tcb[d] = t;
  ridb[d] = r;
}

// ---- kernel 3: per-expert MLP; direct gather; weights from L2; 16 waves/CU -
// LDS = 64KB h1 transpose only (8 waves x 8KB) -> 2 blocks/CU. W1/W2 fragments
// stream from Wswz (L2-resident 320KB; 256B/wave/ks). fv pipeline as round 12.
__global__ __launch_bounds__(512, 4) void mlp(
    const float* __restrict__ x, const float* __restrict__ tcb,
    const int* __restrict__ ridb, const int* __restrict__ cnt,
    const unsigned short* __restrict__ Wswz,
    const float* __restrict__ tw1, const float* __restrict__ b1,
    const float* __restrict__ tw2, const float* __restrict__ b2,
    const float* __restrict__ W3, const float* __restrict__ tw3,
    const float* __restrict__ b3, float* __restrict__ out) {
  __shared__ unsigned short h1[8][32 * 128];    // 8 KB per wave, swizzled

  int tid = threadIdx.x;
  int e = blockIdx.x / BPE;
  int bi = blockIdx.x % BPE;
  int n = min(cnt[e * CPAD], CAP);

  int wave = tid >> 6;
  int lane = tid & 63;
  int lr = lane & 15;
  int lq = lane >> 4;

  const char* wp1 = (const char*)(Wswz + (size_t)e * 32768);
  const char* wp2 = wp1 + 32768;
  char* hp = (char*)h1[wave];
  const float* tce = tcb + (size_t)e * CAP;
  const int* ride = ridb + (size_t)e * CAP;

  int nchunk = (n + CHUNK - 1) / CHUNK;

  f32x4u fv0[8], fv1[8];                        // next-chunk f32 fragments

  auto load_meta = [&](int cc, float& ptv, int& prv) {
    int ci = min(cc * CHUNK + wave * 32 + (lane & 31), n - 1);
    ptv = tce[ci];
    prv = ride[ci];
  };
  auto issue_fv = [&](int rvX) {
    int rd0 = __shfl(rvX, lr);
    int rd1 = __shfl(rvX, 16 + lr);
    const float* p0 = x + (size_t)rd0 * 129 + 1 + lq * 8;
    const float* p1 = x + (size_t)rd1 * 129 + 1 + lq * 8;
#pragma unroll
    for (int ks = 0; ks < 4; ++ks) {
      fv0[2 * ks]     = *(const f32x4u*)(p0 + ks * 32);
      fv0[2 * ks + 1] = *(const f32x4u*)(p0 + ks * 32 + 4);
      fv1[2 * ks]     = *(const f32x4u*)(p1 + ks * 32);
      fv1[2 * ks + 1] = *(const f32x4u*)(p1 + ks * 32 + 4);
    }
  };

  float tvA = 0.f, tvB = 0.f;
  int rvA = 0, rvB = 0;
  int c = bi;
  if (c < nchunk) load_meta(c, tvA, rvA);
  if (c + BPE < nchunk) load_meta(c + BPE, tvB, rvB);
  if (c < nchunk) issue_fv(rvA);

  for (; c < nchunk; c += BPE) {
    // convert arrived f32 fragments -> bf16 A (waits on fv vmcnt)
    short8 a0[4], a1[4];
#pragma unroll
    for (int ks = 0; ks < 4; ++ks) {
#pragma unroll
      for (int j = 0; j < 4; ++j) {
        a0[ks][j]     = (short)f2bf(fv0[2 * ks][j]);
        a0[ks][4 + j] = (short)f2bf(fv0[2 * ks + 1][j]);
        a1[ks][j]     = (short)f2bf(fv1[2 * ks][j]);
        a1[ks][4 + j] = (short)f2bf(fv1[2 * ks + 1][j]);
      }
    }

    // prefetch metadata 2 chunks ahead; fragments 1 chunk ahead
    float tvC = 0.f; int rvC = 0;
    if (c + 2 * BPE < nchunk) load_meta(c + 2 * BPE, tvC, rvC);
    if (c + BPE < nchunk) issue_fv(rvB);        // in flight across compute

    int base = c * CHUNK + wave * 32;

    float t0[4], t1[4];
    int ro0[4], ro1[4];
#pragma unroll
    for (int rr = 0; rr < 4; ++rr) {
      t0[rr] = __shfl(tvA, lq * 4 + rr);
      t1[rr] = __shfl(tvA, 16 + lq * 4 + rr);
      ro0[rr] = __shfl(rvA, lq * 4 + rr);
      ro1[rr] = __shfl(rvA, 16 + lq * 4 + rr);
    }

    // ===== layer 1: h1 = relu(f@W1 + t*tw1 + b1) -> per-wave LDS ===========
#pragma unroll
    for (int ct = 0; ct < 8; ++ct) {
      int col = ct * 16 + lr;
      short8 b[4];
#pragma unroll
      for (int ks = 0; ks < 4; ++ks) {
        int bo = (col * 256 + ks * 64 + lq * 16) ^ ((lr & 7) << 4);
        b[ks] = *(const short8*)(wp1 + bo);
      }
      f32x4 acc0 = {0.f, 0.f, 0.f, 0.f};
      f32x4 acc1 = {0.f, 0.f, 0.f, 0.f};
#pragma unroll
      for (int ks = 0; ks < 4; ++ks) {
        acc0 = __builtin_amdgcn_mfma_f32_16x16x32_bf16(a0[ks], b[ks], acc0, 0, 0, 0);
        acc1 = __builtin_amdgcn_mfma_f32_16x16x32_bf16(a1[ks], b[ks], acc1, 0, 0, 0);
      }
      float twv = tw1[e * 128 + col];
      float bv  = b1[e * 128 + col];
#pragma unroll
      for (int rr = 0; rr < 4; ++rr) {
        int r0_ = lq * 4 + rr;
        int r1_ = r0_ + 16;
        float v0 = fmaxf(acc0[rr] + t0[rr] * twv + bv, 0.f);
        float v1 = fmaxf(acc1[rr] + t1[rr] * twv + bv, 0.f);
        *(unsigned short*)(hp + ((r0_ * 256 + col * 2) ^ ((r0_ & 7) << 4))) = f2bf(v0);
        *(unsigned short*)(hp + ((r1_ * 256 + col * 2) ^ ((r1_ & 7) << 4))) = f2bf(v1);
      }
    }

    // wave-local LDS fence between h1 writes and transposed reads (rule 18)
    asm volatile("s_waitcnt lgkmcnt(0)" ::: "memory");
    __builtin_amdgcn_sched_barrier(0);

#pragma unroll
    for (int ks = 0; ks < 4; ++ks) {
      int off0 = (lr * 256 + ks * 64 + lq * 16) ^ ((lr & 7) << 4);
      int off1 = ((16 + lr) * 256 + ks * 64 + lq * 16) ^ ((lr & 7) << 4);
      a0[ks] = *(const short8*)(hp + off0);
      a1[ks] = *(const short8*)(hp + off1);
    }

    // ===== layer 2 + fused layer 3: o += relu(h1@W2 + t*tw2 + b2) * W3 =====
    const float* W3e = W3 + e * 128;
    float o0[4] = {0.f, 0.f, 0.f, 0.f};
    float o1[4] = {0.f, 0.f, 0.f, 0.f};
#pragma unroll
    for (int ct = 0; ct < 8; ++ct) {
      int col = ct * 16 + lr;
      short8 b[4];
#pragma unroll
      for (int ks = 0; ks < 4; ++ks) {
        int bo = (col * 256 + ks * 64 + lq * 16) ^ ((lr & 7) << 4);
        b[ks] = *(const short8*)(wp2 + bo);
      }
      f32x4 acc0 = {0.f, 0.f, 0.f, 0.f};
      f32x4 acc1 = {0.f, 0.f, 0.f, 0.f};
#pragma unroll
      for (int ks = 0; ks < 4; ++ks) {
        acc0 = __builtin_amdgcn_mfma_f32_16x16x32_bf16(a0[ks], b[ks], acc0, 0, 0, 0);
        acc1 = __builtin_amdgcn_mfma_f32_16x16x32_bf16(a1[ks], b[ks], acc1, 0, 0, 0);
      }
      float twv = tw2[e * 128 + col];
      float bv  = b2[e * 128 + col];
      float w3v = W3e[col];
#pragma unroll
      for (int rr = 0; rr < 4; ++rr) {
        float v0 = fmaxf(acc0[rr] + t0[rr] * twv + bv, 0.f);
        float v1 = fmaxf(acc1[rr] + t1[rr] * twv + bv, 0.f);
        o0[rr] += v0 * w3v;
        o1[rr] += v1 * w3v;
      }
    }

#pragma unroll
    for (int rr = 0; rr < 4; ++rr) {
      float s0 = o0[rr], s1 = o1[rr];
      s0 += __shfl_xor(s0, 1);  s1 += __shfl_xor(s1, 1);
      s0 += __shfl_xor(s0, 2);  s1 += __shfl_xor(s1, 2);
      s0 += __shfl_xor(s0, 4);  s1 += __shfl_xor(s1, 4);
      s0 += __shfl_xor(s0, 8);  s1 += __shfl_xor(s1, 8);
      o0[rr] = s0;  o1[rr] = s1;
    }

    if (lr == 0) {
      float tw3v = tw3[e];
      float b3v  = b3[e];
#pragma unroll
      for (int rr = 0; rr < 4; ++rr) {
        if (base + lq * 4 + rr < n)
          out[ro0[rr]] = o0[rr] + t0[rr] * tw3v + b3v;
        if (base + 16 + lq * 4 + rr < n)
          out[ro1[rr]] = o1[rr] + t1[rr] * tw3v + b3v;
      }
    }

    tvA = tvB; rvA = rvB; tvB = tvC; rvB = rvC;
  }
}

extern "C" void kernel_launch(void* const* d_in, const int* in_sizes, int n_in,
                              void* d_out, int out_size, void* d_ws, size_t ws_size,
                              hipStream_t stream) {
  const float* x   = (const float*)d_in[0];
  const float* W1  = (const float*)d_in[1];
  const float* tw1 = (const float*)d_in[2];
  const float* b1  = (const float*)d_in[3];
  const float* W2  = (const float*)d_in[4];
  const float* tw2 = (const float*)d_in[5];
  const float* b2  = (const float*)d_in[6];
  const float* W3  = (const float*)d_in[7];
  const float* tw3 = (const float*)d_in[8];
  const float* b3  = (const float*)d_in[9];
  float* out = (float*)d_out;

  char* ws = (char*)d_ws;
  size_t off = 0;
  int*   cnt   = (int*)(ws + off);   off += 1024;
  float* tcomp = (float*)(ws + off); off += (size_t)NROWS * 4;        // 1 MB
  int*   hist  = (int*)(ws + off);   off += (size_t)NE * NCH * 4;     // 80 KB
  int*   boff  = (int*)(ws + off);   off += (size_t)NE * NCH * 4;     // 80 KB
  int*   ridb  = (int*)(ws + off);   off += (size_t)NE * CAP * 4;
  float* tcb   = (float*)(ws + off); off += (size_t)NE * CAP * 4;
  unsigned short* Wswz = (unsigned short*)(ws + off);                 // 320 KB

  convw<<<640, 256, 0, stream>>>(W1, W2, Wswz);
  thist<<<NROWS / 256, 256, 0, stream>>>(x, tcomp, hist);
  scan<<<NE, 256, 0, stream>>>(hist, boff, cnt);
  perm<<<NROWS / 256, 256, 0, stream>>>(tcomp, boff, tcb, ridb);
  mlp<<<NE * BPE, 512, 0, stream>>>(x, tcb, ridb, cnt, Wswz,
                                    tw1, b1, tw2, b2, W3, tw3, b3, out);
}

// Round 16
// 261.058 us; speedup vs baseline: 1.5458x; 1.5458x over previous
//
#include <hip/hip_runtime.h>

#define NROWS 262144
#define NE 5
#define CAP 57344                 // per-expert capacity (mean 52429, ~24 sigma)
#define NCH 4096                  // 64-row hist chunks
#define BPE 102                   // mlp blocks per expert (510 total ~ 2/CU)
#define CHUNK 256                 // rows per mlp block-iteration (8 waves x 32)
#define CPAD 16                   // counter stride in ints

typedef __attribute__((ext_vector_type(8))) short short8;
typedef __attribute__((ext_vector_type(8))) unsigned short ushort8;
typedef __attribute__((ext_vector_type(4))) float f32x4;
// 16B vector load with only 4B alignment guarantee (f starts at +4B in a row)
typedef __attribute__((ext_vector_type(4), aligned(4))) float f32x4u;

__device__ __forceinline__ unsigned short f2bf(float x) {
  unsigned u = __float_as_uint(x);
  u += 0x7FFF + ((u >> 16) & 1);   // round-to-nearest-even
  return (unsigned short)(u >> 16);
}
__device__ __forceinline__ int eclass(float t) {
  return (t >= 0.2f) + (t >= 0.4f) + (t >= 0.6f) + (t >= 0.8f);
}

// ---- kernel 1: W1,W2 -> bf16 in the SWIZZLED fragment layout ---------------
// Per expert: 16384 ushorts W1 then 16384 W2. Element (col j, k) at byte
// ((j*256 + k*2) ^ ((j&7)<<4)) within its layer. 320 KB total: L2-resident.
__global__ __launch_bounds__(256) void convw(const float* __restrict__ W1,
                                             const float* __restrict__ W2,
                                             unsigned short* __restrict__ Wswz) {
  int idx = blockIdx.x * 256 + threadIdx.x;       // 0 .. 163839
  int which = idx / 81920;
  int rem = idx % 81920;
  int e = rem / 16384;
  int jk = rem % 16384;
  int j = jk >> 7;                // output col
  int k = jk & 127;               // k index
  const float* W = which ? W2 : W1;
  int byteoff = (j * 256 + k * 2) ^ ((j & 7) << 4);
  Wswz[(size_t)e * 32768 + which * 16384 + (byteoff >> 1)] =
      f2bf(W[(size_t)e * 16384 + k * 128 + j]);
}

// ---- kernel A: extract t + per-64-row-chunk expert histogram ---------------
__global__ __launch_bounds__(256) void thist(const float* __restrict__ x,
                                             float* __restrict__ tcomp,
                                             int* __restrict__ hist) {
  __shared__ int hS[4][NE];
  int tid = threadIdx.x;
  int r = blockIdx.x * 256 + tid;
  if (tid < 20) hS[tid / NE][tid % NE] = 0;
  float t = x[(size_t)r * 129];
  int e = eclass(t);
  tcomp[r] = t;
  __syncthreads();
  atomicAdd(&hS[tid >> 6][e], 1);
  __syncthreads();
  if (tid < 20) {
    int sub = tid / NE, ee = tid % NE;
    hist[ee * NCH + blockIdx.x * 4 + sub] = hS[sub][ee];
  }
}

// ---- kernel B: parallel exclusive prefix per expert (5 blocks x 256) -------
__global__ __launch_bounds__(256) void scan(const int* __restrict__ hist,
                                            int* __restrict__ boff,
                                            int* __restrict__ cnt) {
  __shared__ int wsum[4];
  int e = blockIdx.x;
  int tid = threadIdx.x;
  int lane = tid & 63, wv = tid >> 6;

  int v[16];
  int s = 0;
  const int* h = hist + e * NCH + tid * 16;
#pragma unroll
  for (int j = 0; j < 16; ++j) { v[j] = h[j]; s += v[j]; }

  int sc = s;
#pragma unroll
  for (int off = 1; off < 64; off <<= 1) {
    int nv = __shfl_up(sc, off);
    if (lane >= off) sc += nv;
  }
  if (lane == 63) wsum[wv] = sc;
  __syncthreads();
  int wexc = 0;
  for (int k = 0; k < wv; ++k) wexc += wsum[k];
  int run = wexc + sc - s;
  int* bo = boff + e * NCH + tid * 16;
#pragma unroll
  for (int j = 0; j < 16; ++j) { bo[j] = run; run += v[j]; }
  if (tid == 255) cnt[e * CPAD] = run;
}

// ---- kernel C: build permutation only (tcb + ridb) -------------------------
__global__ __launch_bounds__(256) void perm(const float* __restrict__ tcomp,
                                            const int* __restrict__ boff,
                                            float* __restrict__ tcb,
                                            int* __restrict__ ridb) {
  __shared__ int lc[4][NE];
  int tid = threadIdx.x;
  int blk = blockIdx.x;
  int r = blk * 256 + tid;
  int sub = tid >> 6;
  if (tid < 20) lc[tid / NE][tid % NE] = 0;
  float t = tcomp[r];
  int e = eclass(t);
  __syncthreads();
  int lp = atomicAdd(&lc[sub][e], 1);
  int d = e * CAP + min(boff[e * NCH + blk * 4 + sub] + lp, CAP - 1);
  tcb[d] = t;
  ridb[d] = r;
}

// ---- kernel 3: per-expert MLP; direct gather; weights from L2 --------------
// LDS = 64KB h1 transpose only -> 2 blocks/CU (16 waves) IF VGPR<=128.
// __launch_bounds__(512,2) is the configuration that empirically yields
// VGPR=128 with NO spill (round 12); (512,4) spilled the fv pipeline (r15).
__global__ __launch_bounds__(512, 2) void mlp(
    const float* __restrict__ x, const float* __restrict__ tcb,
    const int* __restrict__ ridb, const int* __restrict__ cnt,
    const unsigned short* __restrict__ Wswz,
    const float* __restrict__ tw1, const float* __restrict__ b1,
    const float* __restrict__ tw2, const float* __restrict__ b2,
    const float* __restrict__ W3, const float* __restrict__ tw3,
    const float* __restrict__ b3, float* __restrict__ out) {
  __shared__ unsigned short h1[8][32 * 128];    // 8 KB per wave, swizzled

  int tid = threadIdx.x;
  int e = blockIdx.x / BPE;
  int bi = blockIdx.x % BPE;
  int n = min(cnt[e * CPAD], CAP);

  int wave = tid >> 6;
  int lane = tid & 63;
  int lr = lane & 15;
  int lq = lane >> 4;

  const char* wp1 = (const char*)(Wswz + (size_t)e * 32768);
  const char* wp2 = wp1 + 32768;
  char* hp = (char*)h1[wave];
  const float* tce = tcb + (size_t)e * CAP;
  const int* ride = ridb + (size_t)e * CAP;

  int nchunk = (n + CHUNK - 1) / CHUNK;

  f32x4u fv0[8], fv1[8];                        // next-chunk f32 fragments

  auto load_meta = [&](int cc, float& ptv, int& prv) {
    int ci = min(cc * CHUNK + wave * 32 + (lane & 31), n - 1);
    ptv = tce[ci];
    prv = ride[ci];
  };
  auto issue_fv = [&](int rvX) {
    int rd0 = __shfl(rvX, lr);
    int rd1 = __shfl(rvX, 16 + lr);
    const float* p0 = x + (size_t)rd0 * 129 + 1 + lq * 8;
    const float* p1 = x + (size_t)rd1 * 129 + 1 + lq * 8;
#pragma unroll
    for (int ks = 0; ks < 4; ++ks) {
      fv0[2 * ks]     = *(const f32x4u*)(p0 + ks * 32);
      fv0[2 * ks + 1] = *(const f32x4u*)(p0 + ks * 32 + 4);
      fv1[2 * ks]     = *(const f32x4u*)(p1 + ks * 32);
      fv1[2 * ks + 1] = *(const f32x4u*)(p1 + ks * 32 + 4);
    }
  };

  float tvA = 0.f, tvB = 0.f;
  int rvA = 0, rvB = 0;
  int c = bi;
  if (c < nchunk) load_meta(c, tvA, rvA);
  if (c + BPE < nchunk) load_meta(c + BPE, tvB, rvB);
  if (c < nchunk) issue_fv(rvA);

  for (; c < nchunk; c += BPE) {
    // convert arrived f32 fragments -> bf16 A (waits on fv vmcnt)
    short8 a0[4], a1[4];
#pragma unroll
    for (int ks = 0; ks < 4; ++ks) {
#pragma unroll
      for (int j = 0; j < 4; ++j) {
        a0[ks][j]     = (short)f2bf(fv0[2 * ks][j]);
        a0[ks][4 + j] = (short)f2bf(fv0[2 * ks + 1][j]);
        a1[ks][j]     = (short)f2bf(fv1[2 * ks][j]);
        a1[ks][4 + j] = (short)f2bf(fv1[2 * ks + 1][j]);
      }
    }

    // prefetch metadata 2 chunks ahead; fragments 1 chunk ahead
    float tvC = 0.f; int rvC = 0;
    if (c + 2 * BPE < nchunk) load_meta(c + 2 * BPE, tvC, rvC);
    if (c + BPE < nchunk) issue_fv(rvB);        // in flight across compute

    int base = c * CHUNK + wave * 32;

    float t0[4], t1[4];
    int ro0[4], ro1[4];
#pragma unroll
    for (int rr = 0; rr < 4; ++rr) {
      t0[rr] = __shfl(tvA, lq * 4 + rr);
      t1[rr] = __shfl(tvA, 16 + lq * 4 + rr);
      ro0[rr] = __shfl(rvA, lq * 4 + rr);
      ro1[rr] = __shfl(rvA, 16 + lq * 4 + rr);
    }

    // ===== layer 1: h1 = relu(f@W1 + t*tw1 + b1) -> per-wave LDS ===========
#pragma unroll
    for (int ct = 0; ct < 8; ++ct) {
      int col = ct * 16 + lr;
      short8 b[4];
#pragma unroll
      for (int ks = 0; ks < 4; ++ks) {
        int bo = (col * 256 + ks * 64 + lq * 16) ^ ((lr & 7) << 4);
        b[ks] = *(const short8*)(wp1 + bo);
      }
      f32x4 acc0 = {0.f, 0.f, 0.f, 0.f};
      f32x4 acc1 = {0.f, 0.f, 0.f, 0.f};
#pragma unroll
      for (int ks = 0; ks < 4; ++ks) {
        acc0 = __builtin_amdgcn_mfma_f32_16x16x32_bf16(a0[ks], b[ks], acc0, 0, 0, 0);
        acc1 = __builtin_amdgcn_mfma_f32_16x16x32_bf16(a1[ks], b[ks], acc1, 0, 0, 0);
      }
      float twv = tw1[e * 128 + col];
      float bv  = b1[e * 128 + col];
#pragma unroll
      for (int rr = 0; rr < 4; ++rr) {
        int r0_ = lq * 4 + rr;
        int r1_ = r0_ + 16;
        float v0 = fmaxf(acc0[rr] + t0[rr] * twv + bv, 0.f);
        float v1 = fmaxf(acc1[rr] + t1[rr] * twv + bv, 0.f);
        *(unsigned short*)(hp + ((r0_ * 256 + col * 2) ^ ((r0_ & 7) << 4))) = f2bf(v0);
        *(unsigned short*)(hp + ((r1_ * 256 + col * 2) ^ ((r1_ & 7) << 4))) = f2bf(v1);
      }
    }

    // wave-local LDS fence between h1 writes and transposed reads (rule 18)
    asm volatile("s_waitcnt lgkmcnt(0)" ::: "memory");
    __builtin_amdgcn_sched_barrier(0);

#pragma unroll
    for (int ks = 0; ks < 4; ++ks) {
      int off0 = (lr * 256 + ks * 64 + lq * 16) ^ ((lr & 7) << 4);
      int off1 = ((16 + lr) * 256 + ks * 64 + lq * 16) ^ ((lr & 7) << 4);
      a0[ks] = *(const short8*)(hp + off0);
      a1[ks] = *(const short8*)(hp + off1);
    }

    // ===== layer 2 + fused layer 3: o += relu(h1@W2 + t*tw2 + b2) * W3 =====
    const float* W3e = W3 + e * 128;
    float o0[4] = {0.f, 0.f, 0.f, 0.f};
    float o1[4] = {0.f, 0.f, 0.f, 0.f};
#pragma unroll
    for (int ct = 0; ct < 8; ++ct) {
      int col = ct * 16 + lr;
      short8 b[4];
#pragma unroll
      for (int ks = 0; ks < 4; ++ks) {
        int bo = (col * 256 + ks * 64 + lq * 16) ^ ((lr & 7) << 4);
        b[ks] = *(const short8*)(wp2 + bo);
      }
      f32x4 acc0 = {0.f, 0.f, 0.f, 0.f};
      f32x4 acc1 = {0.f, 0.f, 0.f, 0.f};
#pragma unroll
      for (int ks = 0; ks < 4; ++ks) {
        acc0 = __builtin_amdgcn_mfma_f32_16x16x32_bf16(a0[ks], b[ks], acc0, 0, 0, 0);
        acc1 = __builtin_amdgcn_mfma_f32_16x16x32_bf16(a1[ks], b[ks], acc1, 0, 0, 0);
      }
      float twv = tw2[e * 128 + col];
      float bv  = b2[e * 128 + col];
      float w3v = W3e[col];
#pragma unroll
      for (int rr = 0; rr < 4; ++rr) {
        float v0 = fmaxf(acc0[rr] + t0[rr] * twv + bv, 0.f);
        float v1 = fmaxf(acc1[rr] + t1[rr] * twv + bv, 0.f);
        o0[rr] += v0 * w3v;
        o1[rr] += v1 * w3v;
      }
    }

#pragma unroll
    for (int rr = 0; rr < 4; ++rr) {
      float s0 = o0[rr], s1 = o1[rr];
      s0 += __shfl_xor(s0, 1);  s1 += __shfl_xor(s1, 1);
      s0 += __shfl_xor(s0, 2);  s1 += __shfl_xor(s1, 2);
      s0 += __shfl_xor(s0, 4);  s1 += __shfl_xor(s1, 4);
      s0 += __shfl_xor(s0, 8);  s1 += __shfl_xor(s1, 8);
      o0[rr] = s0;  o1[rr] = s1;
    }

    if (lr == 0) {
      float tw3v = tw3[e];
      float b3v  = b3[e];
#pragma unroll
      for (int rr = 0; rr < 4; ++rr) {
        if (base + lq * 4 + rr < n)
          out[ro0[rr]] = o0[rr] + t0[rr] * tw3v + b3v;
        if (base + 16 + lq * 4 + rr < n)
          out[ro1[rr]] = o1[rr] + t1[rr] * tw3v + b3v;
      }
    }

    tvA = tvB; rvA = rvB; tvB = tvC; rvB = rvC;
  }
}

extern "C" void kernel_launch(void* const* d_in, const int* in_sizes, int n_in,
                              void* d_out, int out_size, void* d_ws, size_t ws_size,
                              hipStream_t stream) {
  const float* x   = (const float*)d_in[0];
  const float* W1  = (const float*)d_in[1];
  const float* tw1 = (const float*)d_in[2];
  const float* b1  = (const float*)d_in[3];
  const float* W2  = (const float*)d_in[4];
  const float* tw2 = (const float*)d_in[5];
  const float* b2  = (const float*)d_in[6];
  const float* W3  = (const float*)d_in[7];
  const float* tw3 = (const float*)d_in[8];
  const float* b3  = (const float*)d_in[9];
  float* out = (float*)d_out;

  char* ws = (char*)d_ws;
  size_t off = 0;
  int*   cnt   = (int*)(ws + off);   off += 1024;
  float* tcomp = (float*)(ws + off); off += (size_t)NROWS * 4;        // 1 MB
  int*   hist  = (int*)(ws + off);   off += (size_t)NE * NCH * 4;     // 80 KB
  int*   boff  = (int*)(ws + off);   off += (size_t)NE * NCH * 4;     // 80 KB
  int*   ridb  = (int*)(ws + off);   off += (size_t)NE * CAP * 4;
  float* tcb   = (float*)(ws + off); off += (size_t)NE * CAP * 4;
  unsigned short* Wswz = (unsigned short*)(ws + off);                 // 320 KB

  convw<<<640, 256, 0, stream>>>(W1, W2, Wswz);
  thist<<<NROWS / 256, 256, 0, stream>>>(x, tcomp, hist);
  scan<<<NE, 256, 0, stream>>>(hist, boff, cnt);
  perm<<<NROWS / 256, 256, 0, stream>>>(tcomp, boff, tcb, ridb);
  mlp<<<NE * BPE, 512, 0, stream>>>(x, tcb, ridb, cnt, Wswz,
                                    tw1, b1, tw2, b2, W3, tw3, b3, out);
}

// Round 17
// 88.911 us; speedup vs baseline: 4.5388x; 2.9362x over previous
//
#include <hip/hip_runtime.h>

#define NROWS 262144
#define NE 5
#define CAP 57344                 // per-expert capacity (mean 52429, ~24 sigma)
#define NCH 4096                  // 64-row hist chunks
#define BPE 51                    // mlp blocks per expert (255 total ~ 1/CU)
#define CHUNK 256                 // rows per mlp block-iteration (8 waves x 32)
#define CPAD 16                   // counter stride in ints

typedef __attribute__((ext_vector_type(8))) short short8;
typedef __attribute__((ext_vector_type(8))) unsigned short ushort8;
typedef __attribute__((ext_vector_type(4))) float f32x4;
// 16B vector load with only 4B alignment guarantee (f starts at +4B in a row)
typedef __attribute__((ext_vector_type(4), aligned(4))) float f32x4u;

__device__ __forceinline__ unsigned short f2bf(float x) {
  unsigned u = __float_as_uint(x);
  u += 0x7FFF + ((u >> 16) & 1);   // round-to-nearest-even
  return (unsigned short)(u >> 16);
}
__device__ __forceinline__ int eclass(float t) {
  return (t >= 0.2f) + (t >= 0.4f) + (t >= 0.6f) + (t >= 0.8f);
}

// ---- kernel 1: W1,W2 -> bf16 in the SWIZZLED LDS-image layout --------------
__global__ __launch_bounds__(256) void convw(const float* __restrict__ W1,
                                             const float* __restrict__ W2,
                                             unsigned short* __restrict__ Wswz) {
  int idx = blockIdx.x * 256 + threadIdx.x;       // 0 .. 163839
  int which = idx / 81920;
  int rem = idx % 81920;
  int e = rem / 16384;
  int jk = rem % 16384;
  int j = jk >> 7;                // output col
  int k = jk & 127;               // k index
  const float* W = which ? W2 : W1;
  int byteoff = (j * 256 + k * 2) ^ ((j & 7) << 4);
  Wswz[(size_t)e * 32768 + which * 16384 + (byteoff >> 1)] =
      f2bf(W[(size_t)e * 16384 + k * 128 + j]);
}

// ---- kernel A: extract t + per-64-row-chunk expert histogram ---------------
__global__ __launch_bounds__(256) void thist(const float* __restrict__ x,
                                             float* __restrict__ tcomp,
                                             int* __restrict__ hist) {
  __shared__ int hS[4][NE];
  int tid = threadIdx.x;
  int r = blockIdx.x * 256 + tid;
  if (tid < 20) hS[tid / NE][tid % NE] = 0;
  float t = x[(size_t)r * 129];
  int e = eclass(t);
  tcomp[r] = t;
  __syncthreads();
  atomicAdd(&hS[tid >> 6][e], 1);
  __syncthreads();
  if (tid < 20) {
    int sub = tid / NE, ee = tid % NE;
    hist[ee * NCH + blockIdx.x * 4 + sub] = hS[sub][ee];
  }
}

// ---- kernel B: parallel exclusive prefix per expert (5 blocks x 256) -------
__global__ __launch_bounds__(256) void scan(const int* __restrict__ hist,
                                            int* __restrict__ boff,
                                            int* __restrict__ cnt) {
  __shared__ int wsum[4];
  int e = blockIdx.x;
  int tid = threadIdx.x;
  int lane = tid & 63, wv = tid >> 6;

  int v[16];
  int s = 0;
  const int* h = hist + e * NCH + tid * 16;
#pragma unroll
  for (int j = 0; j < 16; ++j) { v[j] = h[j]; s += v[j]; }

  int sc = s;
#pragma unroll
  for (int off = 1; off < 64; off <<= 1) {
    int nv = __shfl_up(sc, off);
    if (lane >= off) sc += nv;
  }
  if (lane == 63) wsum[wv] = sc;
  __syncthreads();
  int wexc = 0;
  for (int k = 0; k < wv; ++k) wexc += wsum[k];
  int run = wexc + sc - s;
  int* bo = boff + e * NCH + tid * 16;
#pragma unroll
  for (int j = 0; j < 16; ++j) { bo[j] = run; run += v[j]; }
  if (tid == 255) cnt[e * CPAD] = run;
}

// ---- kernel C: build permutation (tcb + ridb + dstperm) --------------------
__global__ __launch_bounds__(256) void perm(const float* __restrict__ tcomp,
                                            const int* __restrict__ boff,
                                            float* __restrict__ tcb,
                                            int* __restrict__ ridb,
                                            int* __restrict__ dstperm) {
  __shared__ int lc[4][NE];
  int tid = threadIdx.x;
  int blk = blockIdx.x;
  int r = blk * 256 + tid;
  int sub = tid >> 6;
  if (tid < 20) lc[tid / NE][tid % NE] = 0;
  float t = tcomp[r];
  int e = eclass(t);
  __syncthreads();
  int lp = atomicAdd(&lc[sub][e], 1);
  int d = e * CAP + min(boff[e * NCH + blk * 4 + sub] + lp, CAP - 1);
  tcb[d] = t;
  ridb[d] = r;
  dstperm[r] = d;
}

// ---- kernel D: STREAMING compact copy (no LDS, no barrier, no atomic) ------
// 32 threads per row; thread k: one unaligned f32x4u read at row*129+1+4k
// (consecutive lanes cover a dense address range -> line-coalesced) and one
// 8B packed-bf16 store; 32 lanes produce the row's 256B contiguously. Rows
// scattered across experts = allowed write pattern. Max occupancy.
__global__ __launch_bounds__(256) void compact2(
    const float* __restrict__ x, const int* __restrict__ dstperm,
    unsigned short* __restrict__ xc) {
  int tid = threadIdx.x;
  int r = blockIdx.x * 8 + (tid >> 5);
  int k = tid & 31;
  int d = dstperm[r];                            // broadcast within 32 lanes
  f32x4u v = *(const f32x4u*)(x + (size_t)r * 129 + 1 + k * 4);
  unsigned long long p =
      (unsigned long long)f2bf(v[0]) |
      ((unsigned long long)f2bf(v[1]) << 16) |
      ((unsigned long long)f2bf(v[2]) << 32) |
      ((unsigned long long)f2bf(v[3]) << 48);
  *(unsigned long long*)(xc + (size_t)d * 128 + k * 4) = p;
}

// ---- kernel 3: per-expert MLP, weights in LDS, chunk-pipelined xc loads ----
// (round-11 proven version: 512 thr, 128KB LDS, 1 block/CU, VGPR<=128)
__global__ __launch_bounds__(512, 2) void mlp(
    const unsigned short* __restrict__ xc, const float* __restrict__ tcb,
    const int* __restrict__ ridb, const int* __restrict__ cnt,
    const unsigned short* __restrict__ Wswz,
    const float* __restrict__ tw1, const float* __restrict__ b1,
    const float* __restrict__ tw2, const float* __restrict__ b2,
    const float* __restrict__ W3, const float* __restrict__ tw3,
    const float* __restrict__ b3, float* __restrict__ out) {
  __shared__ unsigned short wl[32768];          // 64 KB: W1 swz | W2 swz
  __shared__ unsigned short h1[8][32 * 128];    // 8 KB per wave, swizzled

  int tid = threadIdx.x;
  int e = blockIdx.x / BPE;
  int bi = blockIdx.x % BPE;
  int n = min(cnt[e * CPAD], CAP);

  {
    const ushort8* wsrc = (const ushort8*)(Wswz + (size_t)e * 32768);
    ushort8* wdst = (ushort8*)wl;
#pragma unroll
    for (int i = 0; i < 8; ++i) wdst[i * 512 + tid] = wsrc[i * 512 + tid];
  }
  __syncthreads();

  int wave = tid >> 6;
  int lane = tid & 63;
  int lr = lane & 15;
  int lq = lane >> 4;

  const char* wp1 = (const char*)wl;
  const char* wp2 = (const char*)wl + 32768;
  char* hp = (char*)h1[wave];
  const unsigned short* xce = xc + (size_t)e * CAP * 128;
  const float* tce = tcb + (size_t)e * CAP;
  const int* ride = ridb + (size_t)e * CAP;

  int nchunk = (n + CHUNK - 1) / CHUNK;

  auto loada = [&](int cc, short8 (&pa0)[4], short8 (&pa1)[4],
                   float& ptv, int& prv) {
    int base = cc * CHUNK + wave * 32;
    int ci = min(base + (lane & 31), n - 1);
    ptv = tce[ci];
    prv = ride[ci];
    int row0 = min(base + lr, n - 1);
    int row1 = min(base + 16 + lr, n - 1);
#pragma unroll
    for (int ks = 0; ks < 4; ++ks) {
      pa0[ks] = *(const short8*)(xce + (size_t)row0 * 128 + ks * 32 + lq * 8);
      pa1[ks] = *(const short8*)(xce + (size_t)row1 * 128 + ks * 32 + lq * 8);
    }
  };

  short8 a0[4], a1[4];
  float tv; int rv;
  int c = bi;
  if (c < nchunk) loada(c, a0, a1, tv, rv);

  for (; c < nchunk; ) {
    int cn = c + BPE;
    bool hn = (cn < nchunk);
    short8 na0[4], na1[4];
    float ntv = 0.f; int nrv = 0;
    if (hn) loada(cn, na0, na1, ntv, nrv);      // in flight across compute

    int base = c * CHUNK + wave * 32;

    float t0[4], t1[4];
    int ro0[4], ro1[4];
#pragma unroll
    for (int rr = 0; rr < 4; ++rr) {
      t0[rr] = __shfl(tv, lq * 4 + rr);
      t1[rr] = __shfl(tv, 16 + lq * 4 + rr);
      ro0[rr] = __shfl(rv, lq * 4 + rr);
      ro1[rr] = __shfl(rv, 16 + lq * 4 + rr);
    }

    // ===== layer 1: h1 = relu(f@W1 + t*tw1 + b1) -> per-wave LDS ===========
#pragma unroll
    for (int ct = 0; ct < 8; ++ct) {
      int col = ct * 16 + lr;
      short8 b[4];
#pragma unroll
      for (int ks = 0; ks < 4; ++ks) {
        int bo = (col * 256 + ks * 64 + lq * 16) ^ ((lr & 7) << 4);
        b[ks] = *(const short8*)(wp1 + bo);
      }
      f32x4 acc0 = {0.f, 0.f, 0.f, 0.f};
      f32x4 acc1 = {0.f, 0.f, 0.f, 0.f};
#pragma unroll
      for (int ks = 0; ks < 4; ++ks) {
        acc0 = __builtin_amdgcn_mfma_f32_16x16x32_bf16(a0[ks], b[ks], acc0, 0, 0, 0);
        acc1 = __builtin_amdgcn_mfma_f32_16x16x32_bf16(a1[ks], b[ks], acc1, 0, 0, 0);
      }
      float twv = tw1[e * 128 + col];
      float bv  = b1[e * 128 + col];
#pragma unroll
      for (int rr = 0; rr < 4; ++rr) {
        int r0_ = lq * 4 + rr;
        int r1_ = r0_ + 16;
        float v0 = fmaxf(acc0[rr] + t0[rr] * twv + bv, 0.f);
        float v1 = fmaxf(acc1[rr] + t1[rr] * twv + bv, 0.f);
        *(unsigned short*)(hp + ((r0_ * 256 + col * 2) ^ ((r0_ & 7) << 4))) = f2bf(v0);
        *(unsigned short*)(hp + ((r1_ * 256 + col * 2) ^ ((r1_ & 7) << 4))) = f2bf(v1);
      }
    }

    asm volatile("s_waitcnt lgkmcnt(0)" ::: "memory");
    __builtin_amdgcn_sched_barrier(0);

#pragma unroll
    for (int ks = 0; ks < 4; ++ks) {
      int off0 = (lr * 256 + ks * 64 + lq * 16) ^ ((lr & 7) << 4);
      int off1 = ((16 + lr) * 256 + ks * 64 + lq * 16) ^ ((lr & 7) << 4);
      a0[ks] = *(const short8*)(hp + off0);
      a1[ks] = *(const short8*)(hp + off1);
    }

    // ===== layer 2 + fused layer 3 =====
    const float* W3e = W3 + e * 128;
    float o0[4] = {0.f, 0.f, 0.f, 0.f};
    float o1[4] = {0.f, 0.f, 0.f, 0.f};
#pragma unroll
    for (int ct = 0; ct < 8; ++ct) {
      int col = ct * 16 + lr;
      short8 b[4];
#pragma unroll
      for (int ks = 0; ks < 4; ++ks) {
        int bo = (col * 256 + ks * 64 + lq * 16) ^ ((lr & 7) << 4);
        b[ks] = *(const short8*)(wp2 + bo);
      }
      f32x4 acc0 = {0.f, 0.f, 0.f, 0.f};
      f32x4 acc1 = {0.f, 0.f, 0.f, 0.f};
#pragma unroll
      for (int ks = 0; ks < 4; ++ks) {
        acc0 = __builtin_amdgcn_mfma_f32_16x16x32_bf16(a0[ks], b[ks], acc0, 0, 0, 0);
        acc1 = __builtin_amdgcn_mfma_f32_16x16x32_bf16(a1[ks], b[ks], acc1, 0, 0, 0);
      }
      float twv = tw2[e * 128 + col];
      float bv  = b2[e * 128 + col];
      float w3v = W3e[col];
#pragma unroll
      for (int rr = 0; rr < 4; ++rr) {
        float v0 = fmaxf(acc0[rr] + t0[rr] * twv + bv, 0.f);
        float v1 = fmaxf(acc1[rr] + t1[rr] * twv + bv, 0.f);
        o0[rr] += v0 * w3v;
        o1[rr] += v1 * w3v;
      }
    }

#pragma unroll
    for (int rr = 0; rr < 4; ++rr) {
      float s0 = o0[rr], s1 = o1[rr];
      s0 += __shfl_xor(s0, 1);  s1 += __shfl_xor(s1, 1);
      s0 += __shfl_xor(s0, 2);  s1 += __shfl_xor(s1, 2);
      s0 += __shfl_xor(s0, 4);  s1 += __shfl_xor(s1, 4);
      s0 += __shfl_xor(s0, 8);  s1 += __shfl_xor(s1, 8);
      o0[rr] = s0;  o1[rr] = s1;
    }

    if (lr == 0) {
      float tw3v = tw3[e];
      float b3v  = b3[e];
#pragma unroll
      for (int rr = 0; rr < 4; ++rr) {
        if (base + lq * 4 + rr < n)
          out[ro0[rr]] = o0[rr] + t0[rr] * tw3v + b3v;
        if (base + 16 + lq * 4 + rr < n)
          out[ro1[rr]] = o1[rr] + t1[rr] * tw3v + b3v;
      }
    }

    if (hn) {
#pragma unroll
      for (int ks = 0; ks < 4; ++ks) { a0[ks] = na0[ks]; a1[ks] = na1[ks]; }
      tv = ntv; rv = nrv;
    }
    c = cn;
  }
}

extern "C" void kernel_launch(void* const* d_in, const int* in_sizes, int n_in,
                              void* d_out, int out_size, void* d_ws, size_t ws_size,
                              hipStream_t stream) {
  const float* x   = (const float*)d_in[0];
  const float* W1  = (const float*)d_in[1];
  const float* tw1 = (const float*)d_in[2];
  const float* b1  = (const float*)d_in[3];
  const float* W2  = (const float*)d_in[4];
  const float* tw2 = (const float*)d_in[5];
  const float* b2  = (const float*)d_in[6];
  const float* W3  = (const float*)d_in[7];
  const float* tw3 = (const float*)d_in[8];
  const float* b3  = (const float*)d_in[9];
  float* out = (float*)d_out;

  char* ws = (char*)d_ws;
  size_t off = 0;
  int*   cnt     = (int*)(ws + off);   off += 1024;
  float* tcomp   = (float*)(ws + off); off += (size_t)NROWS * 4;      // 1 MB
  int*   hist    = (int*)(ws + off);   off += (size_t)NE * NCH * 4;   // 80 KB
  int*   boff    = (int*)(ws + off);   off += (size_t)NE * NCH * 4;   // 80 KB
  int*   dstperm = (int*)(ws + off);   off += (size_t)NROWS * 4;      // 1 MB
  int*   ridb    = (int*)(ws + off);   off += (size_t)NE * CAP * 4;
  float* tcb     = (float*)(ws + off); off += (size_t)NE * CAP * 4;
  unsigned short* xc = (unsigned short*)(ws + off); off += (size_t)NE * CAP * 256;
  unsigned short* Wswz = (unsigned short*)(ws + off);                 // 320 KB

  convw<<<640, 256, 0, stream>>>(W1, W2, Wswz);
  thist<<<NROWS / 256, 256, 0, stream>>>(x, tcomp, hist);
  scan<<<NE, 256, 0, stream>>>(hist, boff, cnt);
  perm<<<NROWS / 256, 256, 0, stream>>>(tcomp, boff, tcb, ridb, dstperm);
  compact2<<<NROWS / 8, 256, 0, stream>>>(x, dstperm, xc);
  mlp<<<NE * BPE, 512, 0, stream>>>(xc, tcb, ridb, cnt, Wswz,
                                    tw1, b1, tw2, b2, W3, tw3, b3, out);
}

// Round 18
// 85.464 us; speedup vs baseline: 4.7218x; 1.0403x over previous
//
#include <hip/hip_runtime.h>

#define NROWS 262144
#define NE 5
#define CAP 57344                 // per-expert capacity (mean 52429, ~24 sigma)
#define NCH 8192                  // 32-row hist chunks (match compact3 blocks)
#define BPE 51                    // mlp blocks per expert (255 total ~ 1/CU)
#define CHUNK 256                 // rows per mlp block-iteration (8 waves x 32)
#define CPAD 16                   // counter stride in ints

typedef __attribute__((ext_vector_type(8))) short short8;
typedef __attribute__((ext_vector_type(8))) unsigned short ushort8;
typedef __attribute__((ext_vector_type(4))) float f32x4;
// 16B vector load with only 4B alignment guarantee (f starts at +4B in a row)
typedef __attribute__((ext_vector_type(4), aligned(4))) float f32x4u;

__device__ __forceinline__ unsigned short f2bf(float x) {
  unsigned u = __float_as_uint(x);
  u += 0x7FFF + ((u >> 16) & 1);   // round-to-nearest-even
  return (unsigned short)(u >> 16);
}
__device__ __forceinline__ int eclass(float t) {
  return (t >= 0.2f) + (t >= 0.4f) + (t >= 0.6f) + (t >= 0.8f);
}

// ---- kernel 1: t-histogram (32-row chunks) + fused weight transpose --------
// Blocks 0..639 also convert W1,W2 -> bf16 swizzled-fragment layout (idx-
// guarded); all 1024 blocks histogram their 256 rows into 8 sub-chunks.
__global__ __launch_bounds__(256) void thist_convw(
    const float* __restrict__ x,
    const float* __restrict__ W1, const float* __restrict__ W2,
    unsigned short* __restrict__ Wswz, int* __restrict__ hist) {
  __shared__ int hS[8][NE];
  int tid = threadIdx.x;
  int blk = blockIdx.x;

  // --- fused convw (independent work; 640*256 = 163840 elements) ---
  int idx = blk * 256 + tid;
  if (idx < 163840) {
    int which = idx / 81920;
    int rem = idx % 81920;
    int e = rem / 16384;
    int jk = rem % 16384;
    int j = jk >> 7;
    int k = jk & 127;
    const float* W = which ? W2 : W1;
    int byteoff = (j * 256 + k * 2) ^ ((j & 7) << 4);
    Wswz[(size_t)e * 32768 + which * 16384 + (byteoff >> 1)] =
        f2bf(W[(size_t)e * 16384 + k * 128 + j]);
  }

  // --- t histogram ---
  if (tid < 40) hS[tid / NE][tid % NE] = 0;
  int r = blk * 256 + tid;
  float t = x[(size_t)r * 129];
  int e = eclass(t);
  __syncthreads();
  atomicAdd(&hS[tid >> 5][e], 1);
  __syncthreads();
  if (tid < 40) {
    int sub = tid / NE, ee = tid % NE;
    hist[ee * NCH + blk * 8 + sub] = hS[sub][ee];
  }
}

// ---- kernel B: parallel exclusive prefix per expert (5 blocks x 512) -------
__global__ __launch_bounds__(512) void scan(const int* __restrict__ hist,
                                            int* __restrict__ boff,
                                            int* __restrict__ cnt) {
  __shared__ int wsum[8];
  int e = blockIdx.x;
  int tid = threadIdx.x;
  int lane = tid & 63, wv = tid >> 6;

  int v[16];
  int s = 0;
  const int* h = hist + e * NCH + tid * 16;
#pragma unroll
  for (int j = 0; j < 16; ++j) { v[j] = h[j]; s += v[j]; }

  int sc = s;                                   // wave inclusive scan
#pragma unroll
  for (int off = 1; off < 64; off <<= 1) {
    int nv = __shfl_up(sc, off);
    if (lane >= off) sc += nv;
  }
  if (lane == 63) wsum[wv] = sc;
  __syncthreads();
  int wexc = 0;
  for (int k = 0; k < wv; ++k) wexc += wsum[k];
  int run = wexc + sc - s;                      // exclusive offset for entry 0
  int* bo = boff + e * NCH + tid * 16;
#pragma unroll
  for (int j = 0; j < 16; ++j) { bo[j] = run; run += v[j]; }
  if (tid == 511) cnt[e * CPAD] = run;
}

// ---- kernel C: streaming classify+rank+compact (1 block = 1 hist chunk) ----
// 1024 threads = 32 rows x 32 lanes. Bulk f loads issue first (independent);
// lane k==0 classifies its row and LDS-ranks against boff[e][blk]; all lanes
// then pack/store the in-flight data (row-contiguous 256B writes). No global
// atomics; two cheap barriers; ~2 blocks/CU of pure streaming.
__global__ __launch_bounds__(1024) void compact3(
    const float* __restrict__ x, const int* __restrict__ boff,
    unsigned short* __restrict__ xc, float* __restrict__ tcb,
    int* __restrict__ ridb) {
  __shared__ int lcS[NE];
  __shared__ int dstS[32];

  int tid = threadIdx.x;
  int row = tid >> 5;          // 0..31
  int k = tid & 31;
  int blk = blockIdx.x;
  int r = blk * 32 + row;

  if (tid < NE) lcS[tid] = 0;

  // bulk row data: issued before classify; latency overlaps the rank phase
  f32x4u v = *(const f32x4u*)(x + (size_t)r * 129 + 1 + k * 4);

  float t = 0.f;
  int e = 0;
  if (k == 0) {
    t = x[(size_t)r * 129];
    e = eclass(t);
  }
  __syncthreads();                              // lcS init visible
  if (k == 0) {
    int lp = atomicAdd(&lcS[e], 1);             // LDS atomic, on-CU
    int d = e * CAP + min(boff[e * NCH + blk] + lp, CAP - 1);
    dstS[row] = d;
    tcb[d] = t;
    ridb[d] = r;
  }
  __syncthreads();

  int d = dstS[row];
  unsigned long long p =
      (unsigned long long)f2bf(v[0]) |
      ((unsigned long long)f2bf(v[1]) << 16) |
      ((unsigned long long)f2bf(v[2]) << 32) |
      ((unsigned long long)f2bf(v[3]) << 48);
  *(unsigned long long*)(xc + (size_t)d * 128 + k * 4) = p;
}

// ---- kernel 3: per-expert MLP, weights in LDS, chunk-pipelined xc loads ----
// (round-17 proven version: 512 thr, 128KB LDS, 1 block/CU, VGPR<=128)
__global__ __launch_bounds__(512, 2) void mlp(
    const unsigned short* __restrict__ xc, const float* __restrict__ tcb,
    const int* __restrict__ ridb, const int* __restrict__ cnt,
    const unsigned short* __restrict__ Wswz,
    const float* __restrict__ tw1, const float* __restrict__ b1,
    const float* __restrict__ tw2, const float* __restrict__ b2,
    const float* __restrict__ W3, const float* __restrict__ tw3,
    const float* __restrict__ b3, float* __restrict__ out) {
  __shared__ unsigned short wl[32768];          // 64 KB: W1 swz | W2 swz
  __shared__ unsigned short h1[8][32 * 128];    // 8 KB per wave, swizzled

  int tid = threadIdx.x;
  int e = blockIdx.x / BPE;
  int bi = blockIdx.x % BPE;
  int n = min(cnt[e * CPAD], CAP);

  {
    const ushort8* wsrc = (const ushort8*)(Wswz + (size_t)e * 32768);
    ushort8* wdst = (ushort8*)wl;
#pragma unroll
    for (int i = 0; i < 8; ++i) wdst[i * 512 + tid] = wsrc[i * 512 + tid];
  }
  __syncthreads();

  int wave = tid >> 6;
  int lane = tid & 63;
  int lr = lane & 15;
  int lq = lane >> 4;

  const char* wp1 = (const char*)wl;
  const char* wp2 = (const char*)wl + 32768;
  char* hp = (char*)h1[wave];
  const unsigned short* xce = xc + (size_t)e * CAP * 128;
  const float* tce = tcb + (size_t)e * CAP;
  const int* ride = ridb + (size_t)e * CAP;

  int nchunk = (n + CHUNK - 1) / CHUNK;

  auto loada = [&](int cc, short8 (&pa0)[4], short8 (&pa1)[4],
                   float& ptv, int& prv) {
    int base = cc * CHUNK + wave * 32;
    int ci = min(base + (lane & 31), n - 1);
    ptv = tce[ci];
    prv = ride[ci];
    int row0 = min(base + lr, n - 1);
    int row1 = min(base + 16 + lr, n - 1);
#pragma unroll
    for (int ks = 0; ks < 4; ++ks) {
      pa0[ks] = *(const short8*)(xce + (size_t)row0 * 128 + ks * 32 + lq * 8);
      pa1[ks] = *(const short8*)(xce + (size_t)row1 * 128 + ks * 32 + lq * 8);
    }
  };

  short8 a0[4], a1[4];
  float tv; int rv;
  int c = bi;
  if (c < nchunk) loada(c, a0, a1, tv, rv);

  for (; c < nchunk; ) {
    int cn = c + BPE;
    bool hn = (cn < nchunk);
    short8 na0[4], na1[4];
    float ntv = 0.f; int nrv = 0;
    if (hn) loada(cn, na0, na1, ntv, nrv);      // in flight across compute

    int base = c * CHUNK + wave * 32;

    float t0[4], t1[4];
    int ro0[4], ro1[4];
#pragma unroll
    for (int rr = 0; rr < 4; ++rr) {
      t0[rr] = __shfl(tv, lq * 4 + rr);
      t1[rr] = __shfl(tv, 16 + lq * 4 + rr);
      ro0[rr] = __shfl(rv, lq * 4 + rr);
      ro1[rr] = __shfl(rv, 16 + lq * 4 + rr);
    }

    // ===== layer 1: h1 = relu(f@W1 + t*tw1 + b1) -> per-wave LDS ===========
#pragma unroll
    for (int ct = 0; ct < 8; ++ct) {
      int col = ct * 16 + lr;
      short8 b[4];
#pragma unroll
      for (int ks = 0; ks < 4; ++ks) {
        int bo = (col * 256 + ks * 64 + lq * 16) ^ ((lr & 7) << 4);
        b[ks] = *(const short8*)(wp1 + bo);
      }
      f32x4 acc0 = {0.f, 0.f, 0.f, 0.f};
      f32x4 acc1 = {0.f, 0.f, 0.f, 0.f};
#pragma unroll
      for (int ks = 0; ks < 4; ++ks) {
        acc0 = __builtin_amdgcn_mfma_f32_16x16x32_bf16(a0[ks], b[ks], acc0, 0, 0, 0);
        acc1 = __builtin_amdgcn_mfma_f32_16x16x32_bf16(a1[ks], b[ks], acc1, 0, 0, 0);
      }
      float twv = tw1[e * 128 + col];
      float bv  = b1[e * 128 + col];
#pragma unroll
      for (int rr = 0; rr < 4; ++rr) {
        int r0_ = lq * 4 + rr;
        int r1_ = r0_ + 16;
        float v0 = fmaxf(acc0[rr] + t0[rr] * twv + bv, 0.f);
        float v1 = fmaxf(acc1[rr] + t1[rr] * twv + bv, 0.f);
        *(unsigned short*)(hp + ((r0_ * 256 + col * 2) ^ ((r0_ & 7) << 4))) = f2bf(v0);
        *(unsigned short*)(hp + ((r1_ * 256 + col * 2) ^ ((r1_ & 7) << 4))) = f2bf(v1);
      }
    }

    asm volatile("s_waitcnt lgkmcnt(0)" ::: "memory");
    __builtin_amdgcn_sched_barrier(0);

#pragma unroll
    for (int ks = 0; ks < 4; ++ks) {
      int off0 = (lr * 256 + ks * 64 + lq * 16) ^ ((lr & 7) << 4);
      int off1 = ((16 + lr) * 256 + ks * 64 + lq * 16) ^ ((lr & 7) << 4);
      a0[ks] = *(const short8*)(hp + off0);
      a1[ks] = *(const short8*)(hp + off1);
    }

    // ===== layer 2 + fused layer 3 =====
    const float* W3e = W3 + e * 128;
    float o0[4] = {0.f, 0.f, 0.f, 0.f};
    float o1[4] = {0.f, 0.f, 0.f, 0.f};
#pragma unroll
    for (int ct = 0; ct < 8; ++ct) {
      int col = ct * 16 + lr;
      short8 b[4];
#pragma unroll
      for (int ks = 0; ks < 4; ++ks) {
        int bo = (col * 256 + ks * 64 + lq * 16) ^ ((lr & 7) << 4);
        b[ks] = *(const short8*)(wp2 + bo);
      }
      f32x4 acc0 = {0.f, 0.f, 0.f, 0.f};
      f32x4 acc1 = {0.f, 0.f, 0.f, 0.f};
#pragma unroll
      for (int ks = 0; ks < 4; ++ks) {
        acc0 = __builtin_amdgcn_mfma_f32_16x16x32_bf16(a0[ks], b[ks], acc0, 0, 0, 0);
        acc1 = __builtin_amdgcn_mfma_f32_16x16x32_bf16(a1[ks], b[ks], acc1, 0, 0, 0);
      }
      float twv = tw2[e * 128 + col];
      float bv  = b2[e * 128 + col];
      float w3v = W3e[col];
#pragma unroll
      for (int rr = 0; rr < 4; ++rr) {
        float v0 = fmaxf(acc0[rr] + t0[rr] * twv + bv, 0.f);
        float v1 = fmaxf(acc1[rr] + t1[rr] * twv + bv, 0.f);
        o0[rr] += v0 * w3v;
        o1[rr] += v1 * w3v;
      }
    }

#pragma unroll
    for (int rr = 0; rr < 4; ++rr) {
      float s0 = o0[rr], s1 = o1[rr];
      s0 += __shfl_xor(s0, 1);  s1 += __shfl_xor(s1, 1);
      s0 += __shfl_xor(s0, 2);  s1 += __shfl_xor(s1, 2);
      s0 += __shfl_xor(s0, 4);  s1 += __shfl_xor(s1, 4);
      s0 += __shfl_xor(s0, 8);  s1 += __shfl_xor(s1, 8);
      o0[rr] = s0;  o1[rr] = s1;
    }

    if (lr == 0) {
      float tw3v = tw3[e];
      float b3v  = b3[e];
#pragma unroll
      for (int rr = 0; rr < 4; ++rr) {
        if (base + lq * 4 + rr < n)
          out[ro0[rr]] = o0[rr] + t0[rr] * tw3v + b3v;
        if (base + 16 + lq * 4 + rr < n)
          out[ro1[rr]] = o1[rr] + t1[rr] * tw3v + b3v;
      }
    }

    if (hn) {
#pragma unroll
      for (int ks = 0; ks < 4; ++ks) { a0[ks] = na0[ks]; a1[ks] = na1[ks]; }
      tv = ntv; rv = nrv;
    }
    c = cn;
  }
}

extern "C" void kernel_launch(void* const* d_in, const int* in_sizes, int n_in,
                              void* d_out, int out_size, void* d_ws, size_t ws_size,
                              hipStream_t stream) {
  const float* x   = (const float*)d_in[0];
  const float* W1  = (const float*)d_in[1];
  const float* tw1 = (const float*)d_in[2];
  const float* b1  = (const float*)d_in[3];
  const float* W2  = (const float*)d_in[4];
  const float* tw2 = (const float*)d_in[5];
  const float* b2  = (const float*)d_in[6];
  const float* W3  = (const float*)d_in[7];
  const float* tw3 = (const float*)d_in[8];
  const float* b3  = (const float*)d_in[9];
  float* out = (float*)d_out;

  char* ws = (char*)d_ws;
  size_t off = 0;
  int*   cnt  = (int*)(ws + off);   off += 1024;
  int*   hist = (int*)(ws + off);   off += (size_t)NE * NCH * 4;     // 160 KB
  int*   boff = (int*)(ws + off);   off += (size_t)NE * NCH * 4;     // 160 KB
  int*   ridb = (int*)(ws + off);   off += (size_t)NE * CAP * 4;
  float* tcb  = (float*)(ws + off); off += (size_t)NE * CAP * 4;
  unsigned short* xc = (unsigned short*)(ws + off); off += (size_t)NE * CAP * 256;
  unsigned short* Wswz = (unsigned short*)(ws + off);                // 320 KB

  thist_convw<<<NROWS / 256, 256, 0, stream>>>(x, W1, W2, Wswz, hist);
  scan<<<NE, 512, 0, stream>>>(hist, boff, cnt);
  compact3<<<NROWS / 32, 1024, 0, stream>>>(x, boff, xc, tcb, ridb);
  mlp<<<NE * BPE, 512, 0, stream>>>(xc, tcb, ridb, cnt, Wswz,
                                    tw1, b1, tw2, b2, W3, tw3, b3, out);
}